// Round 6
// baseline (298.746 us; speedup 1.0000x reference)
//
#include <hip/hip_runtime.h>
#include <hip/hip_bf16.h>

typedef __bf16  bf16x8 __attribute__((ext_vector_type(8)));
typedef float   f32x4  __attribute__((ext_vector_type(4)));
using bf16 = __hip_bfloat16;

#define MFMA16(A_, B_, C_) __builtin_amdgcn_mfma_f32_16x16x32_bf16((A_), (B_), (C_), 0, 0, 0)

// Problem constants: B=4, T=2048, C=1024, H=16, D=64. M = B*T = 8192, K = N = 1024.
constexpr float CSCALE = 0.125f * 1.44269504088896340736f;  // 1/sqrt(64) * log2(e)

// --- async global->LDS, 16B per lane (m97 pattern) ---------------------------
__device__ __forceinline__ void gll16(const void* g, void* l) {
    __builtin_amdgcn_global_load_lds(
        (const __attribute__((address_space(1))) void*)g,
        (__attribute__((address_space(3))) void*)l, 16, 0, 0);
}

// --- staging helpers (fallback path) ----------------------------------------
__device__ inline void stage8(bf16* dst, const float* src) {
    const float4 a = *(const float4*)(src);
    const float4 b = *(const float4*)(src + 4);
    union { int4 v; bf16 h[8]; } u;
    u.h[0] = __float2bfloat16(a.x); u.h[1] = __float2bfloat16(a.y);
    u.h[2] = __float2bfloat16(a.z); u.h[3] = __float2bfloat16(a.w);
    u.h[4] = __float2bfloat16(b.x); u.h[5] = __float2bfloat16(b.y);
    u.h[6] = __float2bfloat16(b.z); u.h[7] = __float2bfloat16(b.w);
    *(int4*)dst = u.v;
}
__device__ inline void stage8(bf16* dst, const bf16* src) {
    *(int4*)dst = *(const int4*)src;
}
__device__ inline void store_out(float* p, float v) { *p = v; }
__device__ inline void store_out(bf16*  p, float v) { *p = __float2bfloat16(v); }

// ---------------------------------------------------------------------------
// fp32 -> bf16 convert: x (8M elems) + 4 weight matrices (1M each)
// ---------------------------------------------------------------------------
__global__ __launch_bounds__(256) void cvt_bf16(const float* __restrict__ x,
    const float* __restrict__ W0, const float* __restrict__ W1,
    const float* __restrict__ W2, const float* __restrict__ W3,
    bf16* __restrict__ xb, bf16* __restrict__ Wb)
{
    const size_t nx4 = 2097152;              // 8M / 4
    const size_t total4 = nx4 + 4 * 262144;  // + 4M / 4
    for (size_t v = (size_t)blockIdx.x * 256 + threadIdx.x; v < total4;
         v += (size_t)gridDim.x * 256) {
        const float* src; bf16* dst; size_t off;
        if (v < nx4) { src = x; dst = xb; off = v * 4; }
        else {
            const size_t vw = v - nx4;
            const int w = (int)(vw >> 18);
            off = (vw & 262143) * 4;
            src = (w == 0) ? W0 : (w == 1) ? W1 : (w == 2) ? W2 : W3;
            dst = Wb + ((size_t)w << 20);
        }
        const float4 f = *(const float4*)(src + off);
        union { bf16 h[4]; uint2 u; } pk;
        pk.h[0] = __float2bfloat16(f.x); pk.h[1] = __float2bfloat16(f.y);
        pk.h[2] = __float2bfloat16(f.z); pk.h[3] = __float2bfloat16(f.w);
        *(uint2*)(dst + off) = pk.u;
    }
}

// ---------------------------------------------------------------------------
// bf16 GEMM: BK=64, XOR-swizzled LDS, 32 MFMA per barrier-pair, gll16 staging.
// 1D grid XCD-swizzled. Per-z scale applied in epilogue (Q pre-scaled by
// CSCALE so attention needs no per-S-element multiply).
// mode 0: f32 row-major; 1: bf16 [B][H][T][D]; 2: bf16 [B][H][D][T].
// ---------------------------------------------------------------------------
struct GemmArgs {
    const bf16*  Bm[3];
    const float* bias[3];
    void*        out[3];
    int          mode[3];
    float        scale[3];
};

__global__ __launch_bounds__(256) void gemm_bb(const bf16* __restrict__ A, GemmArgs ga)
{
    __shared__ __align__(16) bf16 sA[128 * 64];
    __shared__ __align__(16) bf16 sB[128 * 64];
    const int id  = blockIdx.x;
    const int z   = id >> 9;
    const int rem = id & 511;
    const int m0 = (rem & 63) * 128;
    const int n0 = (rem >> 6) * 128;
    const bf16*  __restrict__ Bm   = ga.Bm[z];
    const float* __restrict__ bias = ga.bias[z];
    const int mode = ga.mode[z];
    const float sc = ga.scale[z];
    const int tid  = threadIdx.x;
    const int lane = tid & 63;
    const int wave = tid >> 6;
    const int l15  = lane & 15;
    const int quad = lane >> 4;
    const int wm = (wave >> 1) * 64;
    const int wn = (wave & 1) * 64;

    f32x4 acc[4][4] = {};

    for (int k0 = 0; k0 < 1024; k0 += 64) {
#pragma unroll
        for (int s = 0; s < 4; ++s) {
            const int L = s * 256 + tid;
            const int r = L >> 3, kl = L & 7;
            const int kg = (kl ^ (r & 7)) * 8;
            gll16(A  + (size_t)(m0 + r) * 1024 + k0 + kg, &sA[L * 8]);
            gll16(Bm + (size_t)(n0 + r) * 1024 + k0 + kg, &sB[L * 8]);
        }
        __syncthreads();

#pragma unroll
        for (int kstep = 0; kstep < 2; ++kstep) {
            const int cs = ((quad + 4 * kstep) ^ (l15 & 7)) * 8;
            bf16x8 aF[4], bF[4];
#pragma unroll
            for (int i = 0; i < 4; ++i)
                aF[i] = *(const bf16x8*)&sA[(wm + i * 16 + l15) * 64 + cs];
#pragma unroll
            for (int j = 0; j < 4; ++j)
                bF[j] = *(const bf16x8*)&sB[(wn + j * 16 + l15) * 64 + cs];
#pragma unroll
            for (int i = 0; i < 4; ++i)
#pragma unroll
                for (int j = 0; j < 4; ++j)
                    acc[i][j] = MFMA16(aF[i], bF[j], acc[i][j]);
        }
        __syncthreads();
    }

    if (mode == 2) {
        bf16* ob = (bf16*)ga.out[z];
#pragma unroll
        for (int j = 0; j < 4; ++j) {
            const int col = n0 + wn + j * 16 + l15;
            const float bv = bias[col];
            const int h = col >> 6, d = col & 63;
#pragma unroll
            for (int i = 0; i < 4; ++i) {
                const int row0 = m0 + wm + i * 16 + quad * 4;
                const int b = row0 >> 11, t = row0 & 2047;
                union { bf16 hh[4]; uint2 v; } pk;
#pragma unroll
                for (int r = 0; r < 4; ++r)
                    pk.hh[r] = __float2bfloat16((acc[i][j][r] + bv) * sc);
                *(uint2*)&ob[((size_t)(b * 16 + h) * 64 + d) * 2048 + t] = pk.v;
            }
        }
    } else if (mode == 1) {
        bf16* ob = (bf16*)ga.out[z];
#pragma unroll
        for (int j = 0; j < 4; ++j) {
            const int col = n0 + wn + j * 16 + l15;
            const float bv = bias[col];
            const int h = col >> 6, d = col & 63;
#pragma unroll
            for (int i = 0; i < 4; ++i) {
#pragma unroll
                for (int r = 0; r < 4; ++r) {
                    const int row = m0 + wm + i * 16 + quad * 4 + r;
                    const int b = row >> 11, t = row & 2047;
                    ob[((size_t)(b * 16 + h) * 2048 + t) * 64 + d] =
                        __float2bfloat16((acc[i][j][r] + bv) * sc);
                }
            }
        }
    } else {
        float* of = (float*)ga.out[z];
#pragma unroll
        for (int j = 0; j < 4; ++j) {
            const int col = n0 + wn + j * 16 + l15;
            const float bv = bias[col];
#pragma unroll
            for (int i = 0; i < 4; ++i) {
#pragma unroll
                for (int r = 0; r < 4; ++r) {
                    const int row = m0 + wm + i * 16 + quad * 4 + r;
                    of[(size_t)row * 1024 + col] = acc[i][j][r] + bv;
                }
            }
        }
    }
}

// ---------------------------------------------------------------------------
// Fallback GEMM (fp32 staging through VGPRs) — proven Round-2 path + scale.
// ---------------------------------------------------------------------------
template <int MODE, typename AT, typename OT>
__global__ __launch_bounds__(256) void gemm_bt(const AT* __restrict__ A,
                                               const float* __restrict__ Bm,
                                               const float* __restrict__ bias,
                                               OT* __restrict__ Cout, float sc)
{
    __shared__ __align__(16) bf16 sA[128 * 32];
    __shared__ __align__(16) bf16 sB[128 * 32];
    const int tid  = threadIdx.x;
    const int lane = tid & 63;
    const int wave = tid >> 6;
    const int l15  = lane & 15;
    const int quad = lane >> 4;
    const int m0 = blockIdx.x * 128;
    const int n0 = blockIdx.y * 128;
    const int wm = (wave >> 1) * 64;
    const int wn = (wave & 1) * 64;

    f32x4 acc[4][4] = {};

    const int c0 = tid, c1 = tid + 256;
    const size_t aoff0 = (size_t)(m0 + (c0 >> 2)) * 1024 + (c0 & 3) * 8;
    const size_t aoff1 = (size_t)(m0 + (c1 >> 2)) * 1024 + (c1 & 3) * 8;
    const size_t boff0 = (size_t)(n0 + (c0 >> 2)) * 1024 + (c0 & 3) * 8;
    const size_t boff1 = (size_t)(n0 + (c1 >> 2)) * 1024 + (c1 & 3) * 8;

    for (int k0 = 0; k0 < 1024; k0 += 32) {
        stage8(&sA[c0 * 8], A  + aoff0 + k0);
        stage8(&sA[c1 * 8], A  + aoff1 + k0);
        stage8(&sB[c0 * 8], Bm + boff0 + k0);
        stage8(&sB[c1 * 8], Bm + boff1 + k0);
        __syncthreads();

        bf16x8 aF[4], bF[4];
#pragma unroll
        for (int i = 0; i < 4; ++i)
            aF[i] = *(const bf16x8*)&sA[(wm + i * 16 + l15) * 32 + quad * 8];
#pragma unroll
        for (int j = 0; j < 4; ++j)
            bF[j] = *(const bf16x8*)&sB[(wn + j * 16 + l15) * 32 + quad * 8];
#pragma unroll
        for (int i = 0; i < 4; ++i)
#pragma unroll
            for (int j = 0; j < 4; ++j)
                acc[i][j] = MFMA16(aF[i], bF[j], acc[i][j]);
        __syncthreads();
    }

#pragma unroll
    for (int j = 0; j < 4; ++j) {
        const int col = n0 + wn + j * 16 + l15;
        const float bv = bias[col];
#pragma unroll
        for (int i = 0; i < 4; ++i) {
#pragma unroll
            for (int r = 0; r < 4; ++r) {
                const int row = m0 + wm + i * 16 + quad * 4 + r;
                const float v = (acc[i][j][r] + bv) * sc;
                size_t idx;
                if (MODE == 0) idx = (size_t)row * 1024 + col;
                else {
                    const int b = row >> 11, t = row & 2047;
                    const int h = col >> 6,  d = col & 63;
                    if (MODE == 1) idx = ((size_t)(b * 16 + h) * 2048 + t) * 64 + d;
                    else           idx = ((size_t)(b * 16 + h) * 64 + d) * 2048 + t;
                }
                store_out(&Cout[idx], v);
            }
        }
    }
}

// ---------------------------------------------------------------------------
// Flash attention v5: Q pre-scaled (no per-S mul), l-sum via ones-row MFMA
// (no per-S add, no butterflies), gll16+XOR-swizzle K/V staging (no VGPR
// round-trip), 64-key tiles, 2048 single-strip blocks (25.6 KB LDS -> 6
// blocks/CU), XCD-swizzled (id&7 = head group), longest strips first.
// Q,K: [B][H][T][64]; Vt: [B][H][64][T]; Y: [B][T][C] (all bf16).
// ---------------------------------------------------------------------------
__global__ __launch_bounds__(256) void attn_fwd5(const bf16* __restrict__ Q,
                                                 const bf16* __restrict__ K,
                                                 const bf16* __restrict__ Vt,
                                                 bf16* __restrict__ Y)
{
    __shared__ __align__(16) bf16 sK[64 * 64];       // XOR-swizzled chunks
    __shared__ __align__(16) bf16 sV[64 * 64];       // [d][t], XOR-swizzled
    __shared__ __align__(16) bf16 sP[4][16 * 72];    // per-wave P^T [q][t], padded
    const int tid  = threadIdx.x;
    const int lane = tid & 63;
    const int wave = tid >> 6;
    const int l15  = lane & 15;
    const int quad = lane >> 4;

    // XCD swizzle: id&7 = head group; strips descend so long blocks start first
    const int id    = blockIdx.x;
    const int sub   = id >> 3;               // [0,256)
    const int bh    = (id & 7) * 8 + (sub >> 5);
    const int strip = 31 - (sub & 31);
    const int q0    = strip * 64;

    const size_t headQK = (size_t)bh * 2048 * 64;
    const size_t headV  = (size_t)bh * 64 * 2048;
    const int b = bh >> 4, h = bh & 15;

    const int myq = q0 + wave * 16 + l15;
    const bf16* qrow = Q + headQK + (size_t)myq * 64;
    const bf16x8 qF0 = *(const bf16x8*)(qrow + quad * 8);
    const bf16x8 qF1 = *(const bf16x8*)(qrow + 32 + quad * 8);

    bf16x8 onesF;
#pragma unroll
    for (int i = 0; i < 8; ++i) onesF[i] = (__bf16)1.0f;

    f32x4 O[4] = {};   // O^T: lane holds q=l15, d = jd*16 + quad*4 + r
    f32x4 O4  = {};    // ones-row accumulator: every reg = l[q=l15]

    const int L0 = tid, L1 = tid + 256;      // 512 8-elem chunks per 64x64 tile
    const int r0 = L0 >> 3, cg0 = ((L0 & 7) ^ (r0 & 7)) * 8;
    const int r1 = L1 >> 3, cg1 = ((L1 & 7) ^ (r1 & 7)) * 8;
    const int cs0 = (quad ^ (l15 & 7)) * 8;  // LDS chunk for global chunk quad
    const int cs1 = cs0 ^ 32;                // for global chunk quad+4
    bf16* sPw = sP[wave];

    for (int t0 = 0; t0 <= q0; t0 += 64) {
        gll16(K  + headQK + (size_t)(t0 + r0) * 64 + cg0, &sK[L0 * 8]);
        gll16(K  + headQK + (size_t)(t0 + r1) * 64 + cg1, &sK[L1 * 8]);
        gll16(Vt + headV + (size_t)r0 * 2048 + t0 + cg0, &sV[L0 * 8]);
        gll16(Vt + headV + (size_t)r1 * 2048 + t0 + cg1, &sV[L1 * 8]);
        __syncthreads();

        const bool diag = (t0 == q0);
#pragma unroll
        for (int j = 0; j < 4; ++j) {
            const int row = j * 16 + l15;
            const bf16x8 kF0 = *(const bf16x8*)&sK[row * 64 + cs0];
            const bf16x8 kF1 = *(const bf16x8*)&sK[row * 64 + cs1];
            f32x4 zS = {};
            zS = MFMA16(kF0, qF0, zS);
            zS = MFMA16(kF1, qF1, zS);
            union { bf16 hh[4]; uint2 v; } pk;
#pragma unroll
            for (int r = 0; r < 4; ++r) {
                float p = exp2f(zS[r]);                       // Q pre-scaled
                if (diag && (t0 + j * 16 + quad * 4 + r) > myq) p = 0.f;
                pk.hh[r] = __float2bfloat16(p);
            }
            *(uint2*)&sPw[l15 * 72 + j * 16 + quad * 4] = pk.v;
        }

        // O^T += V^T · P^T ;  l += ones · P^T
        const bf16x8 pF0 = *(const bf16x8*)&sPw[l15 * 72 + quad * 8];
        const bf16x8 pF1 = *(const bf16x8*)&sPw[l15 * 72 + 32 + quad * 8];
#pragma unroll
        for (int jd = 0; jd < 4; ++jd) {
            const int vrow = jd * 16 + l15;
            const bf16x8 vF0 = *(const bf16x8*)&sV[vrow * 64 + cs0];
            const bf16x8 vF1 = *(const bf16x8*)&sV[vrow * 64 + cs1];
            O[jd] = MFMA16(vF0, pF0, O[jd]);
            O[jd] = MFMA16(vF1, pF1, O[jd]);
        }
        O4 = MFMA16(onesF, pF0, O4);
        O4 = MFMA16(onesF, pF1, O4);
        __syncthreads();
    }

    const float inv_l = 1.0f / O4[0];
    bf16* yrow = Y + ((size_t)(b * 2048 + myq)) * 1024 + h * 64;
#pragma unroll
    for (int jd = 0; jd < 4; ++jd) {
        union { bf16 hh[4]; uint2 v; } ok;
#pragma unroll
        for (int r = 0; r < 4; ++r)
            ok.hh[r] = __float2bfloat16(O[jd][r] * inv_l);
        *(uint2*)&yrow[jd * 16 + quad * 4] = ok.v;
    }
}

// ---------------------------------------------------------------------------
extern "C" void kernel_launch(void* const* d_in, const int* in_sizes, int n_in,
                              void* d_out, int out_size, void* d_ws, size_t ws_size,
                              hipStream_t stream)
{
    const float* x  = (const float*)d_in[0];
    const float* Wq = (const float*)d_in[1];
    const float* bq = (const float*)d_in[2];
    const float* Wk = (const float*)d_in[3];
    const float* bk = (const float*)d_in[4];
    const float* Wv = (const float*)d_in[5];
    const float* bv = (const float*)d_in[6];
    const float* Wp = (const float*)d_in[7];
    const float* bp = (const float*)d_in[8];
    float* out = (float*)d_out;
    bf16*  ws  = (bf16*)d_ws;

    constexpr size_t NE = (size_t)8192 * 1024;  // 8M elems per [B,T,C] tensor
    bf16* Qw = ws;
    bf16* Kw = ws + NE;
    bf16* Vw = ws + 2 * NE;      // [B][H][D][T]
    dim3 bb(256);

    if (ws_size >= (size_t)36 * 1024 * 1024 * 2) {
        bf16* xb = ws + 3 * NE;                  // aliased with Yw (x dead after QKV)
        bf16* Wb = ws + 4 * NE;                  // 4 x 1M bf16 weights
        bf16* Yw = xb;

        cvt_bf16<<<dim3(1024), bb, 0, stream>>>(x, Wq, Wk, Wv, Wp, xb, Wb);

        GemmArgs gq;
        gq.Bm[0] = Wb;      gq.Bm[1] = Wb + (1u << 20);  gq.Bm[2] = Wb + (2u << 20);
        gq.bias[0] = bq;    gq.bias[1] = bk;             gq.bias[2] = bv;
        gq.out[0] = Qw;     gq.out[1] = Kw;              gq.out[2] = Vw;
        gq.mode[0] = 1;     gq.mode[1] = 1;              gq.mode[2] = 2;
        gq.scale[0] = CSCALE; gq.scale[1] = 1.0f;        gq.scale[2] = 1.0f;
        gemm_bb<<<dim3(1536), bb, 0, stream>>>(xb, gq);

        attn_fwd5<<<dim3(2048), bb, 0, stream>>>(Qw, Kw, Vw, Yw);

        GemmArgs go;
        go.Bm[0] = go.Bm[1] = go.Bm[2] = Wb + ((size_t)3 << 20);
        go.bias[0] = go.bias[1] = go.bias[2] = bp;
        go.out[0] = go.out[1] = go.out[2] = out;
        go.mode[0] = go.mode[1] = go.mode[2] = 0;
        go.scale[0] = go.scale[1] = go.scale[2] = 1.0f;
        gemm_bb<<<dim3(512), bb, 0, stream>>>(Yw, go);
    } else {
        bf16* Yw = ws + 3 * NE;
        dim3 gg(64, 8);
        gemm_bt<1, float, bf16><<<gg, bb, 0, stream>>>(x, Wq, bq, Qw, CSCALE);
        gemm_bt<1, float, bf16><<<gg, bb, 0, stream>>>(x, Wk, bk, Kw, 1.0f);
        gemm_bt<2, float, bf16><<<gg, bb, 0, stream>>>(x, Wv, bv, Vw, 1.0f);
        attn_fwd5<<<dim3(2048), bb, 0, stream>>>(Qw, Kw, Vw, Yw);
        gemm_bt<0, bf16, float><<<gg, bb, 0, stream>>>(Yw, Wp, bp, out, 1.0f);
    }
}

// Round 7
// 252.270 us; speedup vs baseline: 1.1842x; 1.1842x over previous
//
#include <hip/hip_runtime.h>
#include <hip/hip_bf16.h>

typedef __bf16  bf16x8 __attribute__((ext_vector_type(8)));
typedef float   f32x4  __attribute__((ext_vector_type(4)));
using bf16 = __hip_bfloat16;

#define MFMA16(A_, B_, C_) __builtin_amdgcn_mfma_f32_16x16x32_bf16((A_), (B_), (C_), 0, 0, 0)

// Problem constants: B=4, T=2048, C=1024, H=16, D=64. M = B*T = 8192, K = N = 1024.
constexpr float CSCALE = 0.125f * 1.44269504088896340736f;  // 1/sqrt(64) * log2(e)

// --- async global->LDS, 16B per lane (m97 pattern) ---------------------------
__device__ __forceinline__ void gll16(const void* g, void* l) {
    __builtin_amdgcn_global_load_lds(
        (const __attribute__((address_space(1))) void*)g,
        (__attribute__((address_space(3))) void*)l, 16, 0, 0);
}

// --- fast RNE f32->bf16 (bit-identical to __float2bfloat16 for finite x) -----
__device__ __forceinline__ unsigned rne1(float x) {
    unsigned u = __float_as_uint(x);
    return (u + 0x7FFF + ((u >> 16) & 1)) >> 16;
}
__device__ __forceinline__ unsigned rne2(float lo, float hi) {
    unsigned a = __float_as_uint(lo), b = __float_as_uint(hi);
    a = (a + 0x7FFF + ((a >> 16) & 1)) >> 16;
    b = b + 0x7FFF + ((b >> 16) & 1);
    return a | (b & 0xFFFF0000u);
}

// --- staging helpers (fallback path) ----------------------------------------
__device__ inline void stage8(bf16* dst, const float* src) {
    const float4 a = *(const float4*)(src);
    const float4 b = *(const float4*)(src + 4);
    union { int4 v; bf16 h[8]; } u;
    u.h[0] = __float2bfloat16(a.x); u.h[1] = __float2bfloat16(a.y);
    u.h[2] = __float2bfloat16(a.z); u.h[3] = __float2bfloat16(a.w);
    u.h[4] = __float2bfloat16(b.x); u.h[5] = __float2bfloat16(b.y);
    u.h[6] = __float2bfloat16(b.z); u.h[7] = __float2bfloat16(b.w);
    *(int4*)dst = u.v;
}
__device__ inline void stage8(bf16* dst, const bf16* src) {
    *(int4*)dst = *(const int4*)src;
}
__device__ inline void store_out(float* p, float v) { *p = v; }
__device__ inline void store_out(bf16*  p, float v) { *p = __float2bfloat16(v); }

// ---------------------------------------------------------------------------
// fp32 -> bf16 convert: x (8M elems) + 4 weight matrices (1M each)
// ---------------------------------------------------------------------------
__global__ __launch_bounds__(256) void cvt_bf16(const float* __restrict__ x,
    const float* __restrict__ W0, const float* __restrict__ W1,
    const float* __restrict__ W2, const float* __restrict__ W3,
    bf16* __restrict__ xb, bf16* __restrict__ Wb)
{
    const size_t nx4 = 2097152;              // 8M / 4
    const size_t total4 = nx4 + 4 * 262144;  // + 4M / 4
    for (size_t v = (size_t)blockIdx.x * 256 + threadIdx.x; v < total4;
         v += (size_t)gridDim.x * 256) {
        const float* src; bf16* dst; size_t off;
        if (v < nx4) { src = x; dst = xb; off = v * 4; }
        else {
            const size_t vw = v - nx4;
            const int w = (int)(vw >> 18);
            off = (vw & 262143) * 4;
            src = (w == 0) ? W0 : (w == 1) ? W1 : (w == 2) ? W2 : W3;
            dst = Wb + ((size_t)w << 20);
        }
        const float4 f = *(const float4*)(src + off);
        uint2 pk;
        pk.x = rne2(f.x, f.y);
        pk.y = rne2(f.z, f.w);
        *(uint2*)(dst + off) = pk;
    }
}

// ---------------------------------------------------------------------------
// bf16 GEMM: BK=64, XOR-swizzled LDS, 32 MFMA per barrier-pair, gll16 staging.
// 1D grid XCD-swizzled. Per-z scale applied in epilogue (Q pre-scaled by
// CSCALE so attention needs no per-S-element multiply).
// mode 0: f32 row-major; 1: bf16 [B][H][T][D]; 2: bf16 [B][H][D][T].
// ---------------------------------------------------------------------------
struct GemmArgs {
    const bf16*  Bm[3];
    const float* bias[3];
    void*        out[3];
    int          mode[3];
    float        scale[3];
};

__global__ __launch_bounds__(256) void gemm_bb(const bf16* __restrict__ A, GemmArgs ga)
{
    __shared__ __align__(16) bf16 sA[128 * 64];
    __shared__ __align__(16) bf16 sB[128 * 64];
    const int id  = blockIdx.x;
    const int z   = id >> 9;
    const int rem = id & 511;
    const int m0 = (rem & 63) * 128;
    const int n0 = (rem >> 6) * 128;
    const bf16*  __restrict__ Bm   = ga.Bm[z];
    const float* __restrict__ bias = ga.bias[z];
    const int mode = ga.mode[z];
    const float sc = ga.scale[z];
    const int tid  = threadIdx.x;
    const int lane = tid & 63;
    const int wave = tid >> 6;
    const int l15  = lane & 15;
    const int quad = lane >> 4;
    const int wm = (wave >> 1) * 64;
    const int wn = (wave & 1) * 64;

    f32x4 acc[4][4] = {};

    for (int k0 = 0; k0 < 1024; k0 += 64) {
#pragma unroll
        for (int s = 0; s < 4; ++s) {
            const int L = s * 256 + tid;
            const int r = L >> 3, kl = L & 7;
            const int kg = (kl ^ (r & 7)) * 8;
            gll16(A  + (size_t)(m0 + r) * 1024 + k0 + kg, &sA[L * 8]);
            gll16(Bm + (size_t)(n0 + r) * 1024 + k0 + kg, &sB[L * 8]);
        }
        __syncthreads();

#pragma unroll
        for (int kstep = 0; kstep < 2; ++kstep) {
            const int cs = ((quad + 4 * kstep) ^ (l15 & 7)) * 8;
            bf16x8 aF[4], bF[4];
#pragma unroll
            for (int i = 0; i < 4; ++i)
                aF[i] = *(const bf16x8*)&sA[(wm + i * 16 + l15) * 64 + cs];
#pragma unroll
            for (int j = 0; j < 4; ++j)
                bF[j] = *(const bf16x8*)&sB[(wn + j * 16 + l15) * 64 + cs];
#pragma unroll
            for (int i = 0; i < 4; ++i)
#pragma unroll
                for (int j = 0; j < 4; ++j)
                    acc[i][j] = MFMA16(aF[i], bF[j], acc[i][j]);
        }
        __syncthreads();
    }

    if (mode == 2) {
        bf16* ob = (bf16*)ga.out[z];
#pragma unroll
        for (int j = 0; j < 4; ++j) {
            const int col = n0 + wn + j * 16 + l15;
            const float bv = bias[col];
            const int h = col >> 6, d = col & 63;
#pragma unroll
            for (int i = 0; i < 4; ++i) {
                const int row0 = m0 + wm + i * 16 + quad * 4;
                const int b = row0 >> 11, t = row0 & 2047;
                uint2 pk;
                pk.x = rne2((acc[i][j][0] + bv) * sc, (acc[i][j][1] + bv) * sc);
                pk.y = rne2((acc[i][j][2] + bv) * sc, (acc[i][j][3] + bv) * sc);
                *(uint2*)&ob[((size_t)(b * 16 + h) * 64 + d) * 2048 + t] = pk;
            }
        }
    } else if (mode == 1) {
        unsigned short* ob = (unsigned short*)ga.out[z];
#pragma unroll
        for (int j = 0; j < 4; ++j) {
            const int col = n0 + wn + j * 16 + l15;
            const float bv = bias[col];
            const int h = col >> 6, d = col & 63;
#pragma unroll
            for (int i = 0; i < 4; ++i) {
#pragma unroll
                for (int r = 0; r < 4; ++r) {
                    const int row = m0 + wm + i * 16 + quad * 4 + r;
                    const int b = row >> 11, t = row & 2047;
                    ob[((size_t)(b * 16 + h) * 2048 + t) * 64 + d] =
                        (unsigned short)rne1((acc[i][j][r] + bv) * sc);
                }
            }
        }
    } else {
        float* of = (float*)ga.out[z];
#pragma unroll
        for (int j = 0; j < 4; ++j) {
            const int col = n0 + wn + j * 16 + l15;
            const float bv = bias[col];
#pragma unroll
            for (int i = 0; i < 4; ++i) {
#pragma unroll
                for (int r = 0; r < 4; ++r) {
                    const int row = m0 + wm + i * 16 + quad * 4 + r;
                    of[(size_t)row * 1024 + col] = acc[i][j][r] + bv;
                }
            }
        }
    }
}

// ---------------------------------------------------------------------------
// Fallback GEMM (fp32 staging through VGPRs) — proven Round-2 path + scale.
// ---------------------------------------------------------------------------
template <int MODE, typename AT, typename OT>
__global__ __launch_bounds__(256) void gemm_bt(const AT* __restrict__ A,
                                               const float* __restrict__ Bm,
                                               const float* __restrict__ bias,
                                               OT* __restrict__ Cout, float sc)
{
    __shared__ __align__(16) bf16 sA[128 * 32];
    __shared__ __align__(16) bf16 sB[128 * 32];
    const int tid  = threadIdx.x;
    const int lane = tid & 63;
    const int wave = tid >> 6;
    const int l15  = lane & 15;
    const int quad = lane >> 4;
    const int m0 = blockIdx.x * 128;
    const int n0 = blockIdx.y * 128;
    const int wm = (wave >> 1) * 64;
    const int wn = (wave & 1) * 64;

    f32x4 acc[4][4] = {};

    const int c0 = tid, c1 = tid + 256;
    const size_t aoff0 = (size_t)(m0 + (c0 >> 2)) * 1024 + (c0 & 3) * 8;
    const size_t aoff1 = (size_t)(m0 + (c1 >> 2)) * 1024 + (c1 & 3) * 8;
    const size_t boff0 = (size_t)(n0 + (c0 >> 2)) * 1024 + (c0 & 3) * 8;
    const size_t boff1 = (size_t)(n0 + (c1 >> 2)) * 1024 + (c1 & 3) * 8;

    for (int k0 = 0; k0 < 1024; k0 += 32) {
        stage8(&sA[c0 * 8], A  + aoff0 + k0);
        stage8(&sA[c1 * 8], A  + aoff1 + k0);
        stage8(&sB[c0 * 8], Bm + boff0 + k0);
        stage8(&sB[c1 * 8], Bm + boff1 + k0);
        __syncthreads();

        bf16x8 aF[4], bF[4];
#pragma unroll
        for (int i = 0; i < 4; ++i)
            aF[i] = *(const bf16x8*)&sA[(wm + i * 16 + l15) * 32 + quad * 8];
#pragma unroll
        for (int j = 0; j < 4; ++j)
            bF[j] = *(const bf16x8*)&sB[(wn + j * 16 + l15) * 32 + quad * 8];
#pragma unroll
        for (int i = 0; i < 4; ++i)
#pragma unroll
            for (int j = 0; j < 4; ++j)
                acc[i][j] = MFMA16(aF[i], bF[j], acc[i][j]);
        __syncthreads();
    }

#pragma unroll
    for (int j = 0; j < 4; ++j) {
        const int col = n0 + wn + j * 16 + l15;
        const float bv = bias[col];
#pragma unroll
        for (int i = 0; i < 4; ++i) {
#pragma unroll
            for (int r = 0; r < 4; ++r) {
                const int row = m0 + wm + i * 16 + quad * 4 + r;
                const float v = (acc[i][j][r] + bv) * sc;
                size_t idx;
                if (MODE == 0) idx = (size_t)row * 1024 + col;
                else {
                    const int b = row >> 11, t = row & 2047;
                    const int h = col >> 6,  d = col & 63;
                    if (MODE == 1) idx = ((size_t)(b * 16 + h) * 2048 + t) * 64 + d;
                    else           idx = ((size_t)(b * 16 + h) * 64 + d) * 2048 + t;
                }
                store_out(&Cout[idx], v);
            }
        }
    }
}

// ---------------------------------------------------------------------------
// Flash attention v6 = fwd4's proven paired-strip structure (1024 uniform
// 33-tile blocks, id&7 XCD swizzle) + gll16/XOR staging + Q pre-scale +
// ones-MFMA l-sum + raw v_exp_f32 + 3-op RNE bf16 packing + mask-free main
// path (diagonal tile handled in a separate uniform branch).
// Q,K: [B][H][T][64]; Vt: [B][H][64][T]; Y: [B][T][C] (all bf16).
// ---------------------------------------------------------------------------
__global__ __launch_bounds__(256) void attn_fwd6(const bf16* __restrict__ Q,
                                                 const bf16* __restrict__ K,
                                                 const bf16* __restrict__ Vt,
                                                 bf16* __restrict__ Y)
{
    __shared__ __align__(16) bf16 sK[64 * 64];       // XOR-swizzled chunks
    __shared__ __align__(16) bf16 sV[64 * 64];       // [d][t], XOR-swizzled
    __shared__ __align__(16) bf16 sP[4][16 * 72];    // per-wave P^T [q][t], padded
    const int tid  = threadIdx.x;
    const int lane = tid & 63;
    const int wave = tid >> 6;
    const int l15  = lane & 15;
    const int quad = lane >> 4;

    // XCD swizzle: id&7 = head group; paired strips -> uniform 33 tiles/block
    const int id   = blockIdx.x;
    const int sub  = id >> 3;            // [0,128)
    const int bh   = (id & 7) * 8 + (sub >> 4);
    const int pair = sub & 15;

    const size_t headQK = (size_t)bh * 2048 * 64;
    const size_t headV  = (size_t)bh * 64 * 2048;
    const int b = bh >> 4, h = bh & 15;

    bf16x8 onesF;
#pragma unroll
    for (int i = 0; i < 8; ++i) onesF[i] = (__bf16)1.0f;

    const int L0 = tid, L1 = tid + 256;      // 512 8-elem chunks per 64x64 tile
    const int r0 = L0 >> 3, cg0 = ((L0 & 7) ^ (r0 & 7)) * 8;
    const int r1 = L1 >> 3, cg1 = ((L1 & 7) ^ (r1 & 7)) * 8;
    const int cs0 = (quad ^ (l15 & 7)) * 8;  // LDS chunk for global chunk quad
    const int cs1 = cs0 ^ 32;                // for global chunk quad+4
    bf16* sPw = sP[wave];

#pragma unroll
    for (int strip = 0; strip < 2; ++strip) {
        const int qt = strip ? (31 - pair) : pair;
        const int q0 = qt * 64;
        const int myq = q0 + wave * 16 + l15;

        const bf16* qrow = Q + headQK + (size_t)myq * 64;   // Q pre-scaled
        const bf16x8 qF0 = *(const bf16x8*)(qrow + quad * 8);
        const bf16x8 qF1 = *(const bf16x8*)(qrow + 32 + quad * 8);

        f32x4 O[4] = {};   // O^T: lane holds q=l15, d = jd*16 + quad*4 + r
        f32x4 O4  = {};    // ones-row accumulator: every reg = l[q=l15]

        for (int t0 = 0; t0 <= q0; t0 += 64) {
            gll16(K  + headQK + (size_t)(t0 + r0) * 64 + cg0, &sK[L0 * 8]);
            gll16(K  + headQK + (size_t)(t0 + r1) * 64 + cg1, &sK[L1 * 8]);
            gll16(Vt + headV + (size_t)r0 * 2048 + t0 + cg0, &sV[L0 * 8]);
            gll16(Vt + headV + (size_t)r1 * 2048 + t0 + cg1, &sV[L1 * 8]);
            __syncthreads();

            if (t0 == q0) {
                // diagonal tile: masked softmax
#pragma unroll
                for (int j = 0; j < 4; ++j) {
                    const int row = j * 16 + l15;
                    const bf16x8 kF0 = *(const bf16x8*)&sK[row * 64 + cs0];
                    const bf16x8 kF1 = *(const bf16x8*)&sK[row * 64 + cs1];
                    f32x4 zS = {};
                    zS = MFMA16(kF0, qF0, zS);
                    zS = MFMA16(kF1, qF1, zS);
                    float p[4];
#pragma unroll
                    for (int r = 0; r < 4; ++r) {
                        const int tcur = t0 + j * 16 + quad * 4 + r;
                        p[r] = (tcur > myq) ? 0.f : __builtin_amdgcn_exp2f(zS[r]);
                    }
                    uint2 pk = { rne2(p[0], p[1]), rne2(p[2], p[3]) };
                    *(uint2*)&sPw[l15 * 72 + j * 16 + quad * 4] = pk;
                }
            } else {
                // interior tile: mask-free
#pragma unroll
                for (int j = 0; j < 4; ++j) {
                    const int row = j * 16 + l15;
                    const bf16x8 kF0 = *(const bf16x8*)&sK[row * 64 + cs0];
                    const bf16x8 kF1 = *(const bf16x8*)&sK[row * 64 + cs1];
                    f32x4 zS = {};
                    zS = MFMA16(kF0, qF0, zS);
                    zS = MFMA16(kF1, qF1, zS);
                    uint2 pk = { rne2(__builtin_amdgcn_exp2f(zS[0]),
                                      __builtin_amdgcn_exp2f(zS[1])),
                                 rne2(__builtin_amdgcn_exp2f(zS[2]),
                                      __builtin_amdgcn_exp2f(zS[3])) };
                    *(uint2*)&sPw[l15 * 72 + j * 16 + quad * 4] = pk;
                }
            }

            // O^T += V^T · P^T ;  l += ones · P^T
            const bf16x8 pF0 = *(const bf16x8*)&sPw[l15 * 72 + quad * 8];
            const bf16x8 pF1 = *(const bf16x8*)&sPw[l15 * 72 + 32 + quad * 8];
#pragma unroll
            for (int jd = 0; jd < 4; ++jd) {
                const int vrow = jd * 16 + l15;
                const bf16x8 vF0 = *(const bf16x8*)&sV[vrow * 64 + cs0];
                const bf16x8 vF1 = *(const bf16x8*)&sV[vrow * 64 + cs1];
                O[jd] = MFMA16(vF0, pF0, O[jd]);
                O[jd] = MFMA16(vF1, pF1, O[jd]);
            }
            O4 = MFMA16(onesF, pF0, O4);
            O4 = MFMA16(onesF, pF1, O4);
            __syncthreads();
        }

        const float inv_l = 1.0f / O4[0];
        bf16* yrow = Y + ((size_t)(b * 2048 + myq)) * 1024 + h * 64;
#pragma unroll
        for (int jd = 0; jd < 4; ++jd) {
            uint2 ok = { rne2(O[jd][0] * inv_l, O[jd][1] * inv_l),
                         rne2(O[jd][2] * inv_l, O[jd][3] * inv_l) };
            *(uint2*)&yrow[jd * 16 + quad * 4] = ok;
        }
    }
}

// ---------------------------------------------------------------------------
extern "C" void kernel_launch(void* const* d_in, const int* in_sizes, int n_in,
                              void* d_out, int out_size, void* d_ws, size_t ws_size,
                              hipStream_t stream)
{
    const float* x  = (const float*)d_in[0];
    const float* Wq = (const float*)d_in[1];
    const float* bq = (const float*)d_in[2];
    const float* Wk = (const float*)d_in[3];
    const float* bk = (const float*)d_in[4];
    const float* Wv = (const float*)d_in[5];
    const float* bv = (const float*)d_in[6];
    const float* Wp = (const float*)d_in[7];
    const float* bp = (const float*)d_in[8];
    float* out = (float*)d_out;
    bf16*  ws  = (bf16*)d_ws;

    constexpr size_t NE = (size_t)8192 * 1024;  // 8M elems per [B,T,C] tensor
    bf16* Qw = ws;
    bf16* Kw = ws + NE;
    bf16* Vw = ws + 2 * NE;      // [B][H][D][T]
    dim3 bb(256);

    if (ws_size >= (size_t)36 * 1024 * 1024 * 2) {
        bf16* xb = ws + 3 * NE;                  // aliased with Yw (x dead after QKV)
        bf16* Wb = ws + 4 * NE;                  // 4 x 1M bf16 weights
        bf16* Yw = xb;

        cvt_bf16<<<dim3(1024), bb, 0, stream>>>(x, Wq, Wk, Wv, Wp, xb, Wb);

        GemmArgs gq;
        gq.Bm[0] = Wb;      gq.Bm[1] = Wb + (1u << 20);  gq.Bm[2] = Wb + (2u << 20);
        gq.bias[0] = bq;    gq.bias[1] = bk;             gq.bias[2] = bv;
        gq.out[0] = Qw;     gq.out[1] = Kw;              gq.out[2] = Vw;
        gq.mode[0] = 1;     gq.mode[1] = 1;              gq.mode[2] = 2;
        gq.scale[0] = CSCALE; gq.scale[1] = 1.0f;        gq.scale[2] = 1.0f;
        gemm_bb<<<dim3(1536), bb, 0, stream>>>(xb, gq);

        attn_fwd6<<<dim3(1024), bb, 0, stream>>>(Qw, Kw, Vw, Yw);

        GemmArgs go;
        go.Bm[0] = go.Bm[1] = go.Bm[2] = Wb + ((size_t)3 << 20);
        go.bias[0] = go.bias[1] = go.bias[2] = bp;
        go.out[0] = go.out[1] = go.out[2] = out;
        go.mode[0] = go.mode[1] = go.mode[2] = 0;
        go.scale[0] = go.scale[1] = go.scale[2] = 1.0f;
        gemm_bb<<<dim3(512), bb, 0, stream>>>(Yw, go);
    } else {
        bf16* Yw = ws + 3 * NE;
        dim3 gg(64, 8);
        gemm_bt<1, float, bf16><<<gg, bb, 0, stream>>>(x, Wq, bq, Qw, CSCALE);
        gemm_bt<1, float, bf16><<<gg, bb, 0, stream>>>(x, Wk, bk, Kw, 1.0f);
        gemm_bt<2, float, bf16><<<gg, bb, 0, stream>>>(x, Wv, bv, Vw, 1.0f);
        attn_fwd6<<<dim3(1024), bb, 0, stream>>>(Qw, Kw, Vw, Yw);
        gemm_bt<0, bf16, float><<<gg, bb, 0, stream>>>(Yw, Wp, bp, out, 1.0f);
    }
}

// Round 8
// 249.328 us; speedup vs baseline: 1.1982x; 1.0118x over previous
//
#include <hip/hip_runtime.h>
#include <hip/hip_bf16.h>

typedef __bf16  bf16x8 __attribute__((ext_vector_type(8)));
typedef float   f32x4  __attribute__((ext_vector_type(4)));
typedef float   f32x16 __attribute__((ext_vector_type(16)));
using bf16 = __hip_bfloat16;

#define MFMA16(A_, B_, C_) __builtin_amdgcn_mfma_f32_16x16x32_bf16((A_), (B_), (C_), 0, 0, 0)
#define MFMA32(A_, B_, C_) __builtin_amdgcn_mfma_f32_32x32x16_bf16((A_), (B_), (C_), 0, 0, 0)

// Problem constants: B=4, T=2048, C=1024, H=16, D=64. M = B*T = 8192, K = N = 1024.
constexpr float CSCALE = 0.125f * 1.44269504088896340736f;  // 1/sqrt(64) * log2(e)

// --- async global->LDS, 16B per lane (m97 pattern) ---------------------------
__device__ __forceinline__ void gll16(const void* g, void* l) {
    __builtin_amdgcn_global_load_lds(
        (const __attribute__((address_space(1))) void*)g,
        (__attribute__((address_space(3))) void*)l, 16, 0, 0);
}

// --- fast RNE f32->bf16 (bit-identical to __float2bfloat16 for finite x) -----
__device__ __forceinline__ unsigned rne1(float x) {
    unsigned u = __float_as_uint(x);
    return (u + 0x7FFF + ((u >> 16) & 1)) >> 16;
}
__device__ __forceinline__ unsigned rne2(float lo, float hi) {
    unsigned a = __float_as_uint(lo), b = __float_as_uint(hi);
    a = (a + 0x7FFF + ((a >> 16) & 1)) >> 16;
    b = b + 0x7FFF + ((b >> 16) & 1);
    return a | (b & 0xFFFF0000u);
}

// --- staging helpers (fallback path) ----------------------------------------
__device__ inline void stage8(bf16* dst, const float* src) {
    const float4 a = *(const float4*)(src);
    const float4 b = *(const float4*)(src + 4);
    union { int4 v; bf16 h[8]; } u;
    u.h[0] = __float2bfloat16(a.x); u.h[1] = __float2bfloat16(a.y);
    u.h[2] = __float2bfloat16(a.z); u.h[3] = __float2bfloat16(a.w);
    u.h[4] = __float2bfloat16(b.x); u.h[5] = __float2bfloat16(b.y);
    u.h[6] = __float2bfloat16(b.z); u.h[7] = __float2bfloat16(b.w);
    *(int4*)dst = u.v;
}
__device__ inline void stage8(bf16* dst, const bf16* src) {
    *(int4*)dst = *(const int4*)src;
}
__device__ inline void store_out(float* p, float v) { *p = v; }
__device__ inline void store_out(bf16*  p, float v) { *p = __float2bfloat16(v); }

// ---------------------------------------------------------------------------
// fp32 -> bf16 convert: x (8M elems) + 4 weight matrices (1M each)
// ---------------------------------------------------------------------------
__global__ __launch_bounds__(256) void cvt_bf16(const float* __restrict__ x,
    const float* __restrict__ W0, const float* __restrict__ W1,
    const float* __restrict__ W2, const float* __restrict__ W3,
    bf16* __restrict__ xb, bf16* __restrict__ Wb)
{
    const size_t nx4 = 2097152;              // 8M / 4
    const size_t total4 = nx4 + 4 * 262144;  // + 4M / 4
    for (size_t v = (size_t)blockIdx.x * 256 + threadIdx.x; v < total4;
         v += (size_t)gridDim.x * 256) {
        const float* src; bf16* dst; size_t off;
        if (v < nx4) { src = x; dst = xb; off = v * 4; }
        else {
            const size_t vw = v - nx4;
            const int w = (int)(vw >> 18);
            off = (vw & 262143) * 4;
            src = (w == 0) ? W0 : (w == 1) ? W1 : (w == 2) ? W2 : W3;
            dst = Wb + ((size_t)w << 20);
        }
        const float4 f = *(const float4*)(src + off);
        uint2 pk;
        pk.x = rne2(f.x, f.y);
        pk.y = rne2(f.z, f.w);
        *(uint2*)(dst + off) = pk;
    }
}

// ---------------------------------------------------------------------------
// bf16 GEMM v3: 32x32x16 MFMA (2495 TF shape, half the instruction count of
// 16x16x32 at equal LDS traffic), BK=64, XOR-swizzled LDS (conflicts = 0,
// measured), gll16 staging, 1D grid XCD-swizzled.
// Per wave: 64x64 output = 2x2 of 32x32, acc 64 VGPRs.
// C/D layout (HW-verified m74/m101): col=lane&31, row=(reg&3)+8*(reg>>2)+4*hi.
// A/B frags: row(col)=lane&31, k = hi*8 + j  (k-permutation-safe: A and B use
// the same convention, so any mapping error cancels in the contraction).
// mode 0: f32 row-major; 1: bf16 [B][H][T][D]; 2: bf16 [B][H][D][T] (8B packed).
// ---------------------------------------------------------------------------
struct GemmArgs {
    const bf16*  Bm[3];
    const float* bias[3];
    void*        out[3];
    int          mode[3];
    float        scale[3];
};

__global__ __launch_bounds__(256) void gemm_bb(const bf16* __restrict__ A, GemmArgs ga)
{
    __shared__ __align__(16) bf16 sA[128 * 64];
    __shared__ __align__(16) bf16 sB[128 * 64];
    const int id  = blockIdx.x;
    const int z   = id >> 9;
    const int rem = id & 511;
    const int m0 = (rem & 63) * 128;
    const int n0 = (rem >> 6) * 128;
    const bf16*  __restrict__ Bm   = ga.Bm[z];
    const float* __restrict__ bias = ga.bias[z];
    const int mode = ga.mode[z];
    const float sc = ga.scale[z];
    const int tid  = threadIdx.x;
    const int lane = tid & 63;
    const int wave = tid >> 6;
    const int l31  = lane & 31;
    const int hi   = lane >> 5;
    const int wm = (wave >> 1) * 64;
    const int wn = (wave & 1) * 64;

    f32x16 acc[2][2] = {};

    for (int k0 = 0; k0 < 1024; k0 += 64) {
#pragma unroll
        for (int s = 0; s < 4; ++s) {
            const int L = s * 256 + tid;
            const int r = L >> 3, kl = L & 7;
            const int kg = (kl ^ (r & 7)) * 8;
            gll16(A  + (size_t)(m0 + r) * 1024 + k0 + kg, &sA[L * 8]);
            gll16(Bm + (size_t)(n0 + r) * 1024 + k0 + kg, &sB[L * 8]);
        }
        __syncthreads();

#pragma unroll
        for (int kk = 0; kk < 4; ++kk) {
            const int ch = kk * 2 + hi;          // pre-swizzle chunk index
            bf16x8 aF[2], bF[2];
#pragma unroll
            for (int i = 0; i < 2; ++i) {
                const int row = wm + i * 32 + l31;
                aF[i] = *(const bf16x8*)&sA[row * 64 + ((ch ^ (row & 7)) * 8)];
            }
#pragma unroll
            for (int j = 0; j < 2; ++j) {
                const int col = wn + j * 32 + l31;
                bF[j] = *(const bf16x8*)&sB[col * 64 + ((ch ^ (col & 7)) * 8)];
            }
#pragma unroll
            for (int i = 0; i < 2; ++i)
#pragma unroll
                for (int j = 0; j < 2; ++j)
                    acc[i][j] = MFMA32(aF[i], bF[j], acc[i][j]);
        }
        __syncthreads();
    }

    if (mode == 2) {
        bf16* ob = (bf16*)ga.out[z];
#pragma unroll
        for (int j = 0; j < 2; ++j) {
            const int col = n0 + wn + j * 32 + l31;
            const float bv = bias[col];
            const int h = col >> 6, d = col & 63;
#pragma unroll
            for (int i = 0; i < 2; ++i) {
#pragma unroll
                for (int g = 0; g < 4; ++g) {
                    const int row0 = m0 + wm + i * 32 + g * 8 + hi * 4;  // 4 consecutive t
                    const int b = row0 >> 11, t = row0 & 2047;
                    uint2 pk;
                    pk.x = rne2((acc[i][j][4 * g + 0] + bv) * sc,
                                (acc[i][j][4 * g + 1] + bv) * sc);
                    pk.y = rne2((acc[i][j][4 * g + 2] + bv) * sc,
                                (acc[i][j][4 * g + 3] + bv) * sc);
                    *(uint2*)&ob[((size_t)(b * 16 + h) * 64 + d) * 2048 + t] = pk;
                }
            }
        }
    } else if (mode == 1) {
        unsigned short* ob = (unsigned short*)ga.out[z];
#pragma unroll
        for (int j = 0; j < 2; ++j) {
            const int col = n0 + wn + j * 32 + l31;
            const float bv = bias[col];
            const int h = col >> 6, d = col & 63;
#pragma unroll
            for (int i = 0; i < 2; ++i) {
#pragma unroll
                for (int reg = 0; reg < 16; ++reg) {
                    const int row = m0 + wm + i * 32 + (reg & 3) + 8 * (reg >> 2) + 4 * hi;
                    const int b = row >> 11, t = row & 2047;
                    ob[((size_t)(b * 16 + h) * 2048 + t) * 64 + d] =
                        (unsigned short)rne1((acc[i][j][reg] + bv) * sc);
                }
            }
        }
    } else {
        float* of = (float*)ga.out[z];
#pragma unroll
        for (int j = 0; j < 2; ++j) {
            const int col = n0 + wn + j * 32 + l31;
            const float bv = bias[col];
#pragma unroll
            for (int i = 0; i < 2; ++i) {
#pragma unroll
                for (int reg = 0; reg < 16; ++reg) {
                    const int row = m0 + wm + i * 32 + (reg & 3) + 8 * (reg >> 2) + 4 * hi;
                    of[(size_t)row * 1024 + col] = acc[i][j][reg] + bv;
                }
            }
        }
    }
}

// ---------------------------------------------------------------------------
// Fallback GEMM (fp32 staging through VGPRs) — proven Round-2 path + scale.
// ---------------------------------------------------------------------------
template <int MODE, typename AT, typename OT>
__global__ __launch_bounds__(256) void gemm_bt(const AT* __restrict__ A,
                                               const float* __restrict__ Bm,
                                               const float* __restrict__ bias,
                                               OT* __restrict__ Cout, float sc)
{
    __shared__ __align__(16) bf16 sA[128 * 32];
    __shared__ __align__(16) bf16 sB[128 * 32];
    const int tid  = threadIdx.x;
    const int lane = tid & 63;
    const int wave = tid >> 6;
    const int l15  = lane & 15;
    const int quad = lane >> 4;
    const int m0 = blockIdx.x * 128;
    const int n0 = blockIdx.y * 128;
    const int wm = (wave >> 1) * 64;
    const int wn = (wave & 1) * 64;

    f32x4 acc[4][4] = {};

    const int c0 = tid, c1 = tid + 256;
    const size_t aoff0 = (size_t)(m0 + (c0 >> 2)) * 1024 + (c0 & 3) * 8;
    const size_t aoff1 = (size_t)(m0 + (c1 >> 2)) * 1024 + (c1 & 3) * 8;
    const size_t boff0 = (size_t)(n0 + (c0 >> 2)) * 1024 + (c0 & 3) * 8;
    const size_t boff1 = (size_t)(n0 + (c1 >> 2)) * 1024 + (c1 & 3) * 8;

    for (int k0 = 0; k0 < 1024; k0 += 32) {
        stage8(&sA[c0 * 8], A  + aoff0 + k0);
        stage8(&sA[c1 * 8], A  + aoff1 + k0);
        stage8(&sB[c0 * 8], Bm + boff0 + k0);
        stage8(&sB[c1 * 8], Bm + boff1 + k0);
        __syncthreads();

        bf16x8 aF[4], bF[4];
#pragma unroll
        for (int i = 0; i < 4; ++i)
            aF[i] = *(const bf16x8*)&sA[(wm + i * 16 + l15) * 32 + quad * 8];
#pragma unroll
        for (int j = 0; j < 4; ++j)
            bF[j] = *(const bf16x8*)&sB[(wn + j * 16 + l15) * 32 + quad * 8];
#pragma unroll
        for (int i = 0; i < 4; ++i)
#pragma unroll
            for (int j = 0; j < 4; ++j)
                acc[i][j] = MFMA16(aF[i], bF[j], acc[i][j]);
        __syncthreads();
    }

#pragma unroll
    for (int j = 0; j < 4; ++j) {
        const int col = n0 + wn + j * 16 + l15;
        const float bv = bias[col];
#pragma unroll
        for (int i = 0; i < 4; ++i) {
#pragma unroll
            for (int r = 0; r < 4; ++r) {
                const int row = m0 + wm + i * 16 + quad * 4 + r;
                const float v = (acc[i][j][r] + bv) * sc;
                size_t idx;
                if (MODE == 0) idx = (size_t)row * 1024 + col;
                else {
                    const int b = row >> 11, t = row & 2047;
                    const int h = col >> 6,  d = col & 63;
                    if (MODE == 1) idx = ((size_t)(b * 16 + h) * 2048 + t) * 64 + d;
                    else           idx = ((size_t)(b * 16 + h) * 64 + d) * 2048 + t;
                }
                store_out(&Cout[idx], v);
            }
        }
    }
}

// ---------------------------------------------------------------------------
// Flash attention v6 (unchanged from round 7): paired-strip 1024 uniform
// blocks, id&7 XCD swizzle, gll16/XOR staging, Q pre-scale, ones-MFMA l-sum,
// raw v_exp_f32, 3-op RNE packing, mask-free interior tiles.
// Q,K: [B][H][T][64]; Vt: [B][H][64][T]; Y: [B][T][C] (all bf16).
// ---------------------------------------------------------------------------
__global__ __launch_bounds__(256) void attn_fwd6(const bf16* __restrict__ Q,
                                                 const bf16* __restrict__ K,
                                                 const bf16* __restrict__ Vt,
                                                 bf16* __restrict__ Y)
{
    __shared__ __align__(16) bf16 sK[64 * 64];       // XOR-swizzled chunks
    __shared__ __align__(16) bf16 sV[64 * 64];       // [d][t], XOR-swizzled
    __shared__ __align__(16) bf16 sP[4][16 * 72];    // per-wave P^T [q][t], padded
    const int tid  = threadIdx.x;
    const int lane = tid & 63;
    const int wave = tid >> 6;
    const int l15  = lane & 15;
    const int quad = lane >> 4;

    const int id   = blockIdx.x;
    const int sub  = id >> 3;            // [0,128)
    const int bh   = (id & 7) * 8 + (sub >> 4);
    const int pair = sub & 15;

    const size_t headQK = (size_t)bh * 2048 * 64;
    const size_t headV  = (size_t)bh * 64 * 2048;
    const int b = bh >> 4, h = bh & 15;

    bf16x8 onesF;
#pragma unroll
    for (int i = 0; i < 8; ++i) onesF[i] = (__bf16)1.0f;

    const int L0 = tid, L1 = tid + 256;      // 512 8-elem chunks per 64x64 tile
    const int r0 = L0 >> 3, cg0 = ((L0 & 7) ^ (r0 & 7)) * 8;
    const int r1 = L1 >> 3, cg1 = ((L1 & 7) ^ (r1 & 7)) * 8;
    const int cs0 = (quad ^ (l15 & 7)) * 8;
    const int cs1 = cs0 ^ 32;
    bf16* sPw = sP[wave];

#pragma unroll
    for (int strip = 0; strip < 2; ++strip) {
        const int qt = strip ? (31 - pair) : pair;
        const int q0 = qt * 64;
        const int myq = q0 + wave * 16 + l15;

        const bf16* qrow = Q + headQK + (size_t)myq * 64;   // Q pre-scaled
        const bf16x8 qF0 = *(const bf16x8*)(qrow + quad * 8);
        const bf16x8 qF1 = *(const bf16x8*)(qrow + 32 + quad * 8);

        f32x4 O[4] = {};   // O^T: lane holds q=l15, d = jd*16 + quad*4 + r
        f32x4 O4  = {};    // ones-row accumulator: every reg = l[q=l15]

        for (int t0 = 0; t0 <= q0; t0 += 64) {
            gll16(K  + headQK + (size_t)(t0 + r0) * 64 + cg0, &sK[L0 * 8]);
            gll16(K  + headQK + (size_t)(t0 + r1) * 64 + cg1, &sK[L1 * 8]);
            gll16(Vt + headV + (size_t)r0 * 2048 + t0 + cg0, &sV[L0 * 8]);
            gll16(Vt + headV + (size_t)r1 * 2048 + t0 + cg1, &sV[L1 * 8]);
            __syncthreads();

            if (t0 == q0) {
#pragma unroll
                for (int j = 0; j < 4; ++j) {
                    const int row = j * 16 + l15;
                    const bf16x8 kF0 = *(const bf16x8*)&sK[row * 64 + cs0];
                    const bf16x8 kF1 = *(const bf16x8*)&sK[row * 64 + cs1];
                    f32x4 zS = {};
                    zS = MFMA16(kF0, qF0, zS);
                    zS = MFMA16(kF1, qF1, zS);
                    float p[4];
#pragma unroll
                    for (int r = 0; r < 4; ++r) {
                        const int tcur = t0 + j * 16 + quad * 4 + r;
                        p[r] = (tcur > myq) ? 0.f : __builtin_amdgcn_exp2f(zS[r]);
                    }
                    uint2 pk = { rne2(p[0], p[1]), rne2(p[2], p[3]) };
                    *(uint2*)&sPw[l15 * 72 + j * 16 + quad * 4] = pk;
                }
            } else {
#pragma unroll
                for (int j = 0; j < 4; ++j) {
                    const int row = j * 16 + l15;
                    const bf16x8 kF0 = *(const bf16x8*)&sK[row * 64 + cs0];
                    const bf16x8 kF1 = *(const bf16x8*)&sK[row * 64 + cs1];
                    f32x4 zS = {};
                    zS = MFMA16(kF0, qF0, zS);
                    zS = MFMA16(kF1, qF1, zS);
                    uint2 pk = { rne2(__builtin_amdgcn_exp2f(zS[0]),
                                      __builtin_amdgcn_exp2f(zS[1])),
                                 rne2(__builtin_amdgcn_exp2f(zS[2]),
                                      __builtin_amdgcn_exp2f(zS[3])) };
                    *(uint2*)&sPw[l15 * 72 + j * 16 + quad * 4] = pk;
                }
            }

            const bf16x8 pF0 = *(const bf16x8*)&sPw[l15 * 72 + quad * 8];
            const bf16x8 pF1 = *(const bf16x8*)&sPw[l15 * 72 + 32 + quad * 8];
#pragma unroll
            for (int jd = 0; jd < 4; ++jd) {
                const int vrow = jd * 16 + l15;
                const bf16x8 vF0 = *(const bf16x8*)&sV[vrow * 64 + cs0];
                const bf16x8 vF1 = *(const bf16x8*)&sV[vrow * 64 + cs1];
                O[jd] = MFMA16(vF0, pF0, O[jd]);
                O[jd] = MFMA16(vF1, pF1, O[jd]);
            }
            O4 = MFMA16(onesF, pF0, O4);
            O4 = MFMA16(onesF, pF1, O4);
            __syncthreads();
        }

        const float inv_l = 1.0f / O4[0];
        bf16* yrow = Y + ((size_t)(b * 2048 + myq)) * 1024 + h * 64;
#pragma unroll
        for (int jd = 0; jd < 4; ++jd) {
            uint2 ok = { rne2(O[jd][0] * inv_l, O[jd][1] * inv_l),
                         rne2(O[jd][2] * inv_l, O[jd][3] * inv_l) };
            *(uint2*)&yrow[jd * 16 + quad * 4] = ok;
        }
    }
}

// ---------------------------------------------------------------------------
extern "C" void kernel_launch(void* const* d_in, const int* in_sizes, int n_in,
                              void* d_out, int out_size, void* d_ws, size_t ws_size,
                              hipStream_t stream)
{
    const float* x  = (const float*)d_in[0];
    const float* Wq = (const float*)d_in[1];
    const float* bq = (const float*)d_in[2];
    const float* Wk = (const float*)d_in[3];
    const float* bk = (const float*)d_in[4];
    const float* Wv = (const float*)d_in[5];
    const float* bv = (const float*)d_in[6];
    const float* Wp = (const float*)d_in[7];
    const float* bp = (const float*)d_in[8];
    float* out = (float*)d_out;
    bf16*  ws  = (bf16*)d_ws;

    constexpr size_t NE = (size_t)8192 * 1024;  // 8M elems per [B,T,C] tensor
    bf16* Qw = ws;
    bf16* Kw = ws + NE;
    bf16* Vw = ws + 2 * NE;      // [B][H][D][T]
    dim3 bb(256);

    if (ws_size >= (size_t)36 * 1024 * 1024 * 2) {
        bf16* xb = ws + 3 * NE;                  // aliased with Yw (x dead after QKV)
        bf16* Wb = ws + 4 * NE;                  // 4 x 1M bf16 weights
        bf16* Yw = xb;

        cvt_bf16<<<dim3(1024), bb, 0, stream>>>(x, Wq, Wk, Wv, Wp, xb, Wb);

        GemmArgs gq;
        gq.Bm[0] = Wb;      gq.Bm[1] = Wb + (1u << 20);  gq.Bm[2] = Wb + (2u << 20);
        gq.bias[0] = bq;    gq.bias[1] = bk;             gq.bias[2] = bv;
        gq.out[0] = Qw;     gq.out[1] = Kw;              gq.out[2] = Vw;
        gq.mode[0] = 1;     gq.mode[1] = 1;              gq.mode[2] = 2;
        gq.scale[0] = CSCALE; gq.scale[1] = 1.0f;        gq.scale[2] = 1.0f;
        gemm_bb<<<dim3(1536), bb, 0, stream>>>(xb, gq);

        attn_fwd6<<<dim3(1024), bb, 0, stream>>>(Qw, Kw, Vw, Yw);

        GemmArgs go;
        go.Bm[0] = go.Bm[1] = go.Bm[2] = Wb + ((size_t)3 << 20);
        go.bias[0] = go.bias[1] = go.bias[2] = bp;
        go.out[0] = go.out[1] = go.out[2] = out;
        go.mode[0] = go.mode[1] = go.mode[2] = 0;
        go.scale[0] = go.scale[1] = go.scale[2] = 1.0f;
        gemm_bb<<<dim3(512), bb, 0, stream>>>(Yw, go);
    } else {
        bf16* Yw = ws + 3 * NE;
        dim3 gg(64, 8);
        gemm_bt<1, float, bf16><<<gg, bb, 0, stream>>>(x, Wq, bq, Qw, CSCALE);
        gemm_bt<1, float, bf16><<<gg, bb, 0, stream>>>(x, Wk, bk, Kw, 1.0f);
        gemm_bt<2, float, bf16><<<gg, bb, 0, stream>>>(x, Wv, bv, Vw, 1.0f);
        attn_fwd6<<<dim3(1024), bb, 0, stream>>>(Qw, Kw, Vw, Yw);
        gemm_bt<0, bf16, float><<<gg, bb, 0, stream>>>(Yw, Wp, bp, out, 1.0f);
    }
}